// Round 3
// baseline (3461.781 us; speedup 1.0000x reference)
//
#include <hip/hip_runtime.h>

#define T_STEPS 4096
#define BATCH   64
#define INDIM   4
#define H       256
#define OUTD    2
#define CHUNK   32          // h-history ring depth (LDS)
#define QPAD    68          // floats per k-quarter in LDS: 64 + 4 pad (bank derotation)
#define HROW    (4*QPAD)    // 272 floats per stored h vector

__device__ __forceinline__ float fast_tanh(float x) {
    float ax = fabsf(x);
    float e  = __expf(-2.0f * ax);
    float r  = (1.0f - e) * __builtin_amdgcn_rcpf(1.0f + e);
    return copysignf(r, x);
}

// 1024 threads = 16 waves = 4 waves/SIMD (1 block/CU). VGPR cap 128:
// 64 pinned weight regs + ~40 working regs -> fits, no spill.
__global__ __launch_bounds__(1024, 4)
void elman_kernel(const float* __restrict__ input,
                  const float* __restrict__ Wi,
                  const float* __restrict__ bi,
                  const float* __restrict__ Wh,
                  const float* __restrict__ bh,
                  const float* __restrict__ Wf,
                  const float* __restrict__ bf,
                  float* __restrict__ out)
{
    const int b  = blockIdx.x;     // batch element (independent recurrence)
    const int t  = threadIdx.x;
    const int r  = t >> 2;         // hidden row 0..255
    const int kq = t & 3;          // k-quarter 0..3

    __shared__ float h_hist[CHUNK][HROW];  // ring of padded h vectors (~34.8 KB)
    __shared__ float wf_lds[OUTD * H];     // output-head weights (2 KB)

    // --- per-thread quarter-row of Wh: 16 float4 = 64 VGPRs ---
    float4 wh[16];
    {
        const float* wrow = Wh + (size_t)r * H + kq * 64;
        #pragma unroll
        for (int j = 0; j < 16; ++j)
            wh[j] = *(const float4*)(wrow + 4 * j);
    }
    // R2 post-mortem: VGPR_Count=60 proved the compiler rematerialized these
    // loads inside the 4096-step loop (256 KB/CU/step from L1/L2 -> 1940
    // cyc/step). Opaque asm makes the values non-rematerializable: the
    // allocator must keep them resident in VGPRs.
    #pragma unroll
    for (int j = 0; j < 16; ++j)
        asm volatile("" : "+v"(wh[j].x), "+v"(wh[j].y), "+v"(wh[j].z), "+v"(wh[j].w));

    const float4 wiv  = *(const float4*)(Wi + r * INDIM);
    const float  bias = bi[r] + bh[r];
    const float  bf0  = bf[0], bf1 = bf[1];

    if (t < OUTD * H) wf_lds[t] = Wf[t];
    if (t < H)        h_hist[CHUNK - 1][(t >> 6) * QPAD + (t & 63)] = 0.0f; // h0 = 0
    __syncthreads();

    // wave-uniform x vector, prefetched one step ahead
    float4 xcur = *(const float4*)(input + (size_t)b * INDIM);  // step 0

    for (int chunk = 0; chunk < T_STEPS / CHUNK; ++chunk) {
        #pragma unroll 1
        for (int i = 0; i < CHUNK; ++i) {
            const int step = chunk * CHUNK + i;
            int s2 = step + 1; if (s2 >= T_STEPS) s2 = T_STEPS - 1;
            float4 xnext = *(const float4*)(input + ((size_t)s2 * BATCH + b) * INDIM);

            // h quarter, broadcast within kq-group; QPAD spreads the 4 groups'
            // lines across disjoint bank quads (no 4-way conflict)
            const float* hb = &h_hist[(i + CHUNK - 1) & (CHUNK - 1)][kq * QPAD];

            float4 acc = make_float4(0.f, 0.f, 0.f, 0.f);
            #pragma unroll
            for (int j = 0; j < 16; ++j) {
                float4 hv = *(const float4*)(hb + 4 * j);
                acc.x = fmaf(wh[j].x, hv.x, acc.x);
                acc.y = fmaf(wh[j].y, hv.y, acc.y);
                acc.z = fmaf(wh[j].z, hv.z, acc.z);
                acc.w = fmaf(wh[j].w, hv.w, acc.w);
            }
            float pre = (acc.x + acc.y) + (acc.z + acc.w);
            if (kq == 0)
                pre += xcur.x * wiv.x + xcur.y * wiv.y +
                       xcur.z * wiv.z + xcur.w * wiv.w + bias;

            // sum the 4 k-quarter partials (lanes t, t^1, t^2 within group)
            pre += __shfl_xor(pre, 1, 64);
            pre += __shfl_xor(pre, 2, 64);

            const float hn = fast_tanh(pre);
            if (kq == 0)
                h_hist[i][(r >> 6) * QPAD + (r & 63)] = hn;

            xcur = xnext;
            __syncthreads();
        }

        // --- deferred output head for this chunk (amortized ~0.5 cyc/step) ---
        {
            const int task = t >> 4;      // 0..63 : (step-in-chunk, out-idx)
            const int s    = task >> 1;   // 0..31
            const int o    = task & 1;
            const int sub  = t & 15;      // 16-float k-segment
            const int q    = sub >> 2;
            const float* hp = &h_hist[s][q * QPAD + (sub & 3) * 16];
            const float* wp = &wf_lds[o * H + sub * 16];

            float a0 = 0.f, a1 = 0.f, a2 = 0.f, a3 = 0.f;
            #pragma unroll
            for (int j = 0; j < 4; ++j) {
                float4 hv = *(const float4*)(hp + 4 * j);
                float4 wv = *(const float4*)(wp + 4 * j);
                a0 = fmaf(hv.x, wv.x, a0);
                a1 = fmaf(hv.y, wv.y, a1);
                a2 = fmaf(hv.z, wv.z, a2);
                a3 = fmaf(hv.w, wv.w, a3);
            }
            float sum = (a0 + a1) + (a2 + a3);
            sum += __shfl_xor(sum, 1, 64);
            sum += __shfl_xor(sum, 2, 64);
            sum += __shfl_xor(sum, 4, 64);
            sum += __shfl_xor(sum, 8, 64);

            if (sub == 0) {
                const float ob = (o == 0) ? bf0 : bf1;
                out[((size_t)(chunk * CHUNK + s) * BATCH + b) * OUTD + o] =
                    fast_tanh(sum + ob);
            }
            __syncthreads();  // protect h_hist before next chunk overwrites
        }
    }
}

extern "C" void kernel_launch(void* const* d_in, const int* in_sizes, int n_in,
                              void* d_out, int out_size, void* d_ws, size_t ws_size,
                              hipStream_t stream) {
    const float* input = (const float*)d_in[0];
    // d_in[1] = target (unused by forward)
    const float* Wi = (const float*)d_in[2];
    const float* bi = (const float*)d_in[3];
    const float* Wh = (const float*)d_in[4];
    const float* bh = (const float*)d_in[5];
    const float* Wf = (const float*)d_in[6];
    const float* bf = (const float*)d_in[7];
    float* out = (float*)d_out;

    elman_kernel<<<dim3(BATCH), dim3(1024), 0, stream>>>(
        input, Wi, bi, Wh, bh, Wf, bf, out);
}

// Round 4
// 3459.135 us; speedup vs baseline: 1.0008x; 1.0008x over previous
//
#include <hip/hip_runtime.h>

#define T_STEPS 4096
#define BATCH   64
#define INDIM   4
#define H       256
#define OUTD    2
#define CHUNK   32          // h-history ring depth (LDS)
#define QPAD    68          // floats per k-quarter in LDS: 64 + 4 pad (bank derotation)
#define HROW    (4*QPAD)    // 272 floats per stored h vector

__device__ __forceinline__ float fast_tanh(float x) {
    float ax = fabsf(x);
    float e  = __expf(-2.0f * ax);
    float r  = (1.0f - e) * __builtin_amdgcn_rcpf(1.0f + e);
    return copysignf(r, x);
}

// 1024 threads = 16 waves = 4 waves/SIMD, 1 block/CU (grid=64 blocks).
// R3 post-mortem: __launch_bounds__(1024,4) only sets a MINIMUM waves/EU;
// the allocator targeted 8 waves/EU (2 blocks/CU), shrank to 60 VGPRs and
// spilled the weight array -> 256 KB/CU/step reloads. waves_per_eu(4,4)
// pins the occupancy target so the allocator gets the full 128-VGPR budget.
__global__ __attribute__((amdgpu_waves_per_eu(4, 4))) __launch_bounds__(1024)
void elman_kernel(const float* __restrict__ input,
                  const float* __restrict__ Wi,
                  const float* __restrict__ bi,
                  const float* __restrict__ Wh,
                  const float* __restrict__ bh,
                  const float* __restrict__ Wf,
                  const float* __restrict__ bf,
                  float* __restrict__ out)
{
    const int b  = blockIdx.x;     // batch element (independent recurrence)
    const int t  = threadIdx.x;
    const int r  = t >> 2;         // hidden row 0..255
    const int kq = t & 3;          // k-quarter 0..3

    __shared__ float h_hist[CHUNK][HROW];  // ring of padded h vectors (~34.8 KB)
    __shared__ float wf_lds[OUTD * H];     // output-head weights (2 KB)

    // --- per-thread quarter-row of Wh: 16 float4 = 64 VGPRs, kept resident ---
    float4 wh[16];
    {
        const float* wrow = Wh + (size_t)r * H + kq * 64;
        #pragma unroll
        for (int j = 0; j < 16; ++j)
            wh[j] = *(const float4*)(wrow + 4 * j);
    }
    #pragma unroll
    for (int j = 0; j < 16; ++j)
        asm volatile("" : "+v"(wh[j].x), "+v"(wh[j].y), "+v"(wh[j].z), "+v"(wh[j].w));

    const float4 wiv  = *(const float4*)(Wi + r * INDIM);
    const float  bias = bi[r] + bh[r];
    const float  bf0  = bf[0], bf1 = bf[1];

    if (t < OUTD * H) wf_lds[t] = Wf[t];
    if (t < H)        h_hist[CHUNK - 1][(t >> 6) * QPAD + (t & 63)] = 0.0f; // h0 = 0
    __syncthreads();

    // wave-uniform x vector, prefetched one step ahead
    float4 xcur = *(const float4*)(input + (size_t)b * INDIM);  // step 0

    for (int chunk = 0; chunk < T_STEPS / CHUNK; ++chunk) {
        #pragma unroll 1
        for (int i = 0; i < CHUNK; ++i) {
            const int step = chunk * CHUNK + i;
            int s2 = step + 1; if (s2 >= T_STEPS) s2 = T_STEPS - 1;
            float4 xnext = *(const float4*)(input + ((size_t)s2 * BATCH + b) * INDIM);

            // h quarter, broadcast within kq-group; QPAD spreads the 4 groups'
            // lines across disjoint bank quads (no 4-way conflict)
            const float* hb = &h_hist[(i + CHUNK - 1) & (CHUNK - 1)][kq * QPAD];

            float4 acc = make_float4(0.f, 0.f, 0.f, 0.f);
            #pragma unroll
            for (int j = 0; j < 16; ++j) {
                float4 hv = *(const float4*)(hb + 4 * j);
                acc.x = fmaf(wh[j].x, hv.x, acc.x);
                acc.y = fmaf(wh[j].y, hv.y, acc.y);
                acc.z = fmaf(wh[j].z, hv.z, acc.z);
                acc.w = fmaf(wh[j].w, hv.w, acc.w);
            }
            float pre = (acc.x + acc.y) + (acc.z + acc.w);
            if (kq == 0)
                pre += xcur.x * wiv.x + xcur.y * wiv.y +
                       xcur.z * wiv.z + xcur.w * wiv.w + bias;

            // sum the 4 k-quarter partials (lanes t, t^1, t^2 within group)
            pre += __shfl_xor(pre, 1, 64);
            pre += __shfl_xor(pre, 2, 64);

            const float hn = fast_tanh(pre);
            if (kq == 0)
                h_hist[i][(r >> 6) * QPAD + (r & 63)] = hn;

            xcur = xnext;
            __syncthreads();
        }

        // --- deferred output head for this chunk (amortized ~0.5 cyc/step) ---
        {
            const int task = t >> 4;      // 0..63 : (step-in-chunk, out-idx)
            const int s    = task >> 1;   // 0..31
            const int o    = task & 1;
            const int sub  = t & 15;      // 16-float k-segment
            const int q    = sub >> 2;
            const float* hp = &h_hist[s][q * QPAD + (sub & 3) * 16];
            const float* wp = &wf_lds[o * H + sub * 16];

            float a0 = 0.f, a1 = 0.f, a2 = 0.f, a3 = 0.f;
            #pragma unroll
            for (int j = 0; j < 4; ++j) {
                float4 hv = *(const float4*)(hp + 4 * j);
                float4 wv = *(const float4*)(wp + 4 * j);
                a0 = fmaf(hv.x, wv.x, a0);
                a1 = fmaf(hv.y, wv.y, a1);
                a2 = fmaf(hv.z, wv.z, a2);
                a3 = fmaf(hv.w, wv.w, a3);
            }
            float sum = (a0 + a1) + (a2 + a3);
            sum += __shfl_xor(sum, 1, 64);
            sum += __shfl_xor(sum, 2, 64);
            sum += __shfl_xor(sum, 4, 64);
            sum += __shfl_xor(sum, 8, 64);

            if (sub == 0) {
                const float ob = (o == 0) ? bf0 : bf1;
                out[((size_t)(chunk * CHUNK + s) * BATCH + b) * OUTD + o] =
                    fast_tanh(sum + ob);
            }
            __syncthreads();  // protect h_hist before next chunk overwrites
        }
    }
}

extern "C" void kernel_launch(void* const* d_in, const int* in_sizes, int n_in,
                              void* d_out, int out_size, void* d_ws, size_t ws_size,
                              hipStream_t stream) {
    const float* input = (const float*)d_in[0];
    // d_in[1] = target (unused by forward)
    const float* Wi = (const float*)d_in[2];
    const float* bi = (const float*)d_in[3];
    const float* Wh = (const float*)d_in[4];
    const float* bh = (const float*)d_in[5];
    const float* Wf = (const float*)d_in[6];
    const float* bf = (const float*)d_in[7];
    float* out = (float*)d_out;

    elman_kernel<<<dim3(BATCH), dim3(1024), 0, stream>>>(
        input, Wi, bi, Wh, bh, Wf, bf, out);
}

// Round 6
// 3187.122 us; speedup vs baseline: 1.0862x; 1.0853x over previous
//
#include <hip/hip_runtime.h>

#define T_STEPS 4096
#define BATCH   64
#define INDIM   4
#define H       256
#define OUTD    2
#define CHUNK   32
// h vector stored as 128 packed-half2 entries (entry e = rows 2e,2e+1),
// slot(e) = e + (e>>4)*4 spreads the 8 ko-groups across 8 distinct bank-quads
#define HSTRIDE 160

typedef __fp16 half2v __attribute__((ext_vector_type(2)));

__device__ __forceinline__ float fast_tanh(float x) {
    float ax = fabsf(x);
    float e  = __expf(-2.0f * ax);
    float r  = (1.0f - e) * __builtin_amdgcn_rcpf(1.0f + e);
    return copysignf(r, x);
}

__device__ __forceinline__ unsigned int slot_of(unsigned int e) {
    return e + ((e >> 4) << 2);
}

// 1024 threads = 16 waves = 4 waves/SIMD, 1 block/CU (grid = 64).
// R4 post-mortem: bottleneck was LDS pipe (256 ds_read_b128/step). This
// version: row-pair blocking (R=2) + packed-f16 v_dot2 -> 64 ds_read_b128
// /step, 32 weight VGPRs, VALU floor halved.
__global__ __attribute__((amdgpu_waves_per_eu(4, 4))) __launch_bounds__(1024)
void elman_kernel(const float* __restrict__ input,
                  const float* __restrict__ Wi,
                  const float* __restrict__ bi,
                  const float* __restrict__ Wh,
                  const float* __restrict__ bh,
                  const float* __restrict__ Wf,
                  const float* __restrict__ bf,
                  float* __restrict__ out)
{
    const int b  = blockIdx.x;
    const int t  = threadIdx.x;
    const int rp = t >> 3;        // row pair 0..127 (rows 2rp, 2rp+1)
    const int ko = t & 7;         // k-eighth: k range [ko*32, ko*32+32)
    const int r0 = rp * 2, r1 = r0 + 1;
    const int k0 = ko * 32;

    __shared__ unsigned int h_hist[CHUNK][HSTRIDE];  // packed half2, 20 KB
    __shared__ unsigned int wf_pk[OUTD * (H / 2)];   // packed Wf, 1 KB

    // --- weights: 2 rows x 32 k's, packed f16 -> 32 VGPRs ---
    half2v w0[16], w1[16];
    {
        const float* p0 = Wh + (size_t)r0 * H + k0;
        const float* p1 = Wh + (size_t)r1 * H + k0;
        #pragma unroll
        for (int j = 0; j < 8; ++j) {
            float4 a = *(const float4*)(p0 + 4 * j);
            float4 c = *(const float4*)(p1 + 4 * j);
            w0[2 * j]     = __builtin_amdgcn_cvt_pkrtz(a.x, a.y);
            w0[2 * j + 1] = __builtin_amdgcn_cvt_pkrtz(a.z, a.w);
            w1[2 * j]     = __builtin_amdgcn_cvt_pkrtz(c.x, c.y);
            w1[2 * j + 1] = __builtin_amdgcn_cvt_pkrtz(c.z, c.w);
        }
    }
    #pragma unroll
    for (int j = 0; j < 16; ++j) {
        float f0 = __builtin_bit_cast(float, w0[j]);
        float f1 = __builtin_bit_cast(float, w1[j]);
        asm volatile("" : "+v"(f0), "+v"(f1));
        w0[j] = __builtin_bit_cast(half2v, f0);
        w1[j] = __builtin_bit_cast(half2v, f1);
    }

    const float4 wi0   = *(const float4*)(Wi + r0 * INDIM);
    const float4 wi1   = *(const float4*)(Wi + r1 * INDIM);
    const float  bias0 = bi[r0] + bh[r0];
    const float  bias1 = bi[r1] + bh[r1];
    const float  bf0   = bf[0], bf1 = bf[1];

    if (t < OUTD * (H / 2)) {
        const int o = t >> 7, e = t & 127;
        wf_pk[t] = __builtin_bit_cast(unsigned int,
            __builtin_amdgcn_cvt_pkrtz(Wf[o * H + 2 * e], Wf[o * H + 2 * e + 1]));
    }
    if (t < H / 2) h_hist[CHUNK - 1][slot_of(t)] = 0u;   // h0 = 0
    __syncthreads();

    float4 xcur = *(const float4*)(input + (size_t)b * INDIM);  // step 0
    const unsigned int rd_off = (unsigned int)(20 * ko);        // slot(ko*16)
    const unsigned int wr_off = slot_of((unsigned int)rp);

    for (int chunk = 0; chunk < T_STEPS / CHUNK; ++chunk) {
        #pragma unroll 1
        for (int i = 0; i < CHUNK; ++i) {
            const int step = chunk * CHUNK + i;
            int s2 = step + 1; if (s2 >= T_STEPS) s2 = T_STEPS - 1;
            float4 xnext = *(const float4*)(input + ((size_t)s2 * BATCH + b) * INDIM);

            const unsigned int* hb = &h_hist[(i + CHUNK - 1) & (CHUNK - 1)][rd_off];
            uint4 a0 = *(const uint4*)(hb + 0);
            uint4 a1 = *(const uint4*)(hb + 4);
            uint4 a2 = *(const uint4*)(hb + 8);
            uint4 a3 = *(const uint4*)(hb + 12);
            unsigned int hw[16] = {a0.x, a0.y, a0.z, a0.w,
                                   a1.x, a1.y, a1.z, a1.w,
                                   a2.x, a2.y, a2.z, a2.w,
                                   a3.x, a3.y, a3.z, a3.w};

            float acc0 = 0.f, acc1 = 0.f;
            #pragma unroll
            for (int j = 0; j < 16; ++j) {
                half2v hv = __builtin_bit_cast(half2v, hw[j]);
                acc0 = __builtin_amdgcn_fdot2(w0[j], hv, acc0, false);
                acc1 = __builtin_amdgcn_fdot2(w1[j], hv, acc1, false);
            }
            // reduce the 8 k-eighth partials (lanes share rp in groups of 8)
            acc0 += __shfl_xor(acc0, 1, 64);  acc1 += __shfl_xor(acc1, 1, 64);
            acc0 += __shfl_xor(acc0, 2, 64);  acc1 += __shfl_xor(acc1, 2, 64);
            acc0 += __shfl_xor(acc0, 4, 64);  acc1 += __shfl_xor(acc1, 4, 64);

            if (ko == 0) {
                float pre0 = acc0 + bias0 +
                    xcur.x * wi0.x + xcur.y * wi0.y + xcur.z * wi0.z + xcur.w * wi0.w;
                float pre1 = acc1 + bias1 +
                    xcur.x * wi1.x + xcur.y * wi1.y + xcur.z * wi1.z + xcur.w * wi1.w;
                half2v pk = __builtin_amdgcn_cvt_pkrtz(fast_tanh(pre0), fast_tanh(pre1));
                h_hist[i][wr_off] = __builtin_bit_cast(unsigned int, pk);
            }

            xcur = xnext;
            __syncthreads();
        }

        // --- deferred output head for this chunk ---
        {
            const int task = t >> 4;     // (step-in-chunk, out-idx)
            const int s    = task >> 1;
            const int o    = task & 1;
            const int sub  = t & 15;     // 8-entry k-segment
            const unsigned int* hp = &h_hist[s][sub * 8 + ((sub >> 1) << 2)];
            const unsigned int* wp = &wf_pk[o * (H / 2) + sub * 8];

            uint4 hA = *(const uint4*)(hp);
            uint4 hB = *(const uint4*)(hp + 4);
            uint4 wA = *(const uint4*)(wp);
            uint4 wB = *(const uint4*)(wp + 4);
            unsigned int hh[8] = {hA.x, hA.y, hA.z, hA.w, hB.x, hB.y, hB.z, hB.w};
            unsigned int ww[8] = {wA.x, wA.y, wA.z, wA.w, wB.x, wB.y, wB.z, wB.w};

            float acc = 0.f;
            #pragma unroll
            for (int j = 0; j < 8; ++j)
                acc = __builtin_amdgcn_fdot2(__builtin_bit_cast(half2v, ww[j]),
                                             __builtin_bit_cast(half2v, hh[j]),
                                             acc, false);
            acc += __shfl_xor(acc, 1, 64);
            acc += __shfl_xor(acc, 2, 64);
            acc += __shfl_xor(acc, 4, 64);
            acc += __shfl_xor(acc, 8, 64);

            if (sub == 0) {
                out[((size_t)(chunk * CHUNK + s) * BATCH + b) * OUTD + o] =
                    fast_tanh(acc + (o ? bf1 : bf0));
            }
            __syncthreads();  // protect ring before next chunk overwrites
        }
    }
}

extern "C" void kernel_launch(void* const* d_in, const int* in_sizes, int n_in,
                              void* d_out, int out_size, void* d_ws, size_t ws_size,
                              hipStream_t stream) {
    const float* input = (const float*)d_in[0];
    // d_in[1] = target (unused by forward)
    const float* Wi = (const float*)d_in[2];
    const float* bi = (const float*)d_in[3];
    const float* Wh = (const float*)d_in[4];
    const float* bh = (const float*)d_in[5];
    const float* Wf = (const float*)d_in[6];
    const float* bf = (const float*)d_in[7];
    float* out = (float*)d_out;

    elman_kernel<<<dim3(BATCH), dim3(1024), 0, stream>>>(
        input, Wi, bi, Wh, bh, Wf, bf, out);
}